// Round 10
// baseline (67.080 us; speedup 1.0000x reference)
//
#include <hip/hip_runtime.h>
#include <hip/hip_bf16.h>
#include <stdint.h>

#define NROWS 100000
#define INDIM 512
#define HID 128
#define NCLS 10
#define LEAKY_ALPHA 0.2f

typedef __bf16 bf16x8_t __attribute__((ext_vector_type(8)));
typedef __bf16 bf16x4_t __attribute__((ext_vector_type(4)));
typedef float f32x4_t __attribute__((ext_vector_type(4)));
typedef unsigned short ushort8_t __attribute__((ext_vector_type(8)));

union Frag {
    bf16x8_t v8;
    bf16x4_t v4[2];
    unsigned short u[8];
};

__device__ __forceinline__ unsigned short f2bf(float x) {
    union { __hip_bfloat16 b; unsigned short u; } cv;
    cv.b = __float2bfloat16(x);
    return cv.u;
}

__device__ __forceinline__ float bf2f(unsigned short u) {
    union { float f; unsigned int i; } v;
    v.i = ((unsigned int)u) << 16;
    return v.f;
}

// Byte address inside an [R x 32] bf16 tile image (rows paired into 128-B
// lines, 16-B units XOR-swizzled by pair&7). Bank-verified round 3.
__device__ __forceinline__ int img_addr(int r, int kk) {
    int p = r >> 1;
    int o = ((r & 1) << 6) | (kk << 1);
    return (p << 7) | ((((o >> 4) ^ (p & 7)) << 4) | (o & 15));
}

__device__ __forceinline__ void gload_lds16(const void* g, void* l) {
    __builtin_amdgcn_global_load_lds(
        (const __attribute__((address_space(1))) unsigned int*)g,
        (__attribute__((address_space(3))) unsigned int*)l, 16, 0, 0);
}

// ---------------- prep: Qimg = swizzled tile images of Q = [C@(W1@V) | C@(W2@V)] ----------------
// 16 blocks; block b produces k-rows [b*32, b*32+32) of both halves.
__global__ __launch_bounds__(256) void k_prep(
    const float* __restrict__ C, const float* __restrict__ W, const float* __restrict__ V,
    unsigned short* __restrict__ Qimg) {
    __shared__ float Vl[HID * NCLS];
    __shared__ float Pl[2][HID][10];
    __shared__ float Cl[32][132];

    const int tid = threadIdx.x, b = blockIdx.x;
    for (int i = tid; i < HID * NCLS; i += 256) Vl[i] = V[i];
    __syncthreads();

    {
        const int half = tid >> 7, j = tid & 127;
        const float* wr = W + (half * HID + j) * HID;
        float s[NCLS];
#pragma unroll
        for (int c = 0; c < NCLS; ++c) s[c] = 0.f;
        for (int m = 0; m < HID; m += 4) {
            float4 wv = *reinterpret_cast<const float4*>(wr + m);
            float wa[4] = {wv.x, wv.y, wv.z, wv.w};
#pragma unroll
            for (int u = 0; u < 4; ++u)
#pragma unroll
                for (int c = 0; c < NCLS; ++c) s[c] += wa[u] * Vl[(m + u) * NCLS + c];
        }
#pragma unroll
        for (int c = 0; c < NCLS; ++c) Pl[half][j][c] = s[c];
    }
    const int k0 = b << 5;
    {
        const int kr = tid >> 3, ns = (tid & 7) << 4;
        const float4* src = reinterpret_cast<const float4*>(C + (k0 + kr) * HID + ns);
#pragma unroll
        for (int j = 0; j < 4; ++j)
            *reinterpret_cast<float4*>(&Cl[kr][ns + 4 * j]) = src[j];
    }
    __syncthreads();

    for (int e = tid; e < 32 * 32; e += 256) {
        const int n = e >> 5, kl = e & 31;
        const int half = n >> 4, c = n & 15;
        float s = 0.f;
        if (c < NCLS) {
#pragma unroll 4
            for (int j = 0; j < HID; ++j) s += Cl[kl][j] * Pl[half][j][c];
        }
        *(unsigned short*)((char*)Qimg + b * 2048 + img_addr(n, kl)) = f2bf(s);
    }
}

// ---------------- thin GEMM: g = f @ Q ----------------
// BM=128, 4 waves, wave-private single-buffer A staging (8 KB), barrier-free
// main loop, depth-2 register queue, per-block K-phase stagger (HBM channel
// balance). LDS 40 KB -> 4 blocks/CU; whole grid (782) co-resident.
__global__ __launch_bounds__(256, 4) void k_gemm(
    const float* __restrict__ A,             // [NROWS][512] f32
    const unsigned short* __restrict__ Qimg, // 16 x 2KB swizzled tile images
    unsigned short* __restrict__ G)          // [NROWS][32] bf16 (cols 0..9 / 16..25)
{
    __shared__ unsigned short Qs[16384];     // 32 KB
    __shared__ unsigned short As[4096];      // 8 KB single buffer (wave-private rows)

    const int tid  = threadIdx.x;
    const int w    = tid >> 6;
    const int lane = tid & 63;
    const int l15  = lane & 15;
    const int kg   = (lane >> 4) << 2;
    const long row0 = (long)blockIdx.x * 128;
    const int phase = blockIdx.x & 15;       // K-chunk stagger

    // stage all of Q once (wave-uniform dests)
#pragma unroll
    for (int j = 0; j < 8; ++j) {
        const int off = (j * 4 + w) * 1024;
        gload_lds16((const char*)Qimg + off + lane * 16, (char*)Qs + off);
    }

    // A staging: thread -> (row tid>>1, 16-float half); wave-private rows
    const int ar_s = tid >> 1;
    const int kh   = (tid & 1) << 4;
    long gr = row0 + ar_s;
    if (gr >= NROWS) gr = NROWS - 1;
    const float* asrc = A + gr * INDIM + kh;
    const int aw0 = img_addr(ar_s, kh);
    const int aw1 = img_addr(ar_s, kh + 8);

    int ard0[2], ard1[2], brd0[2], brd1[2];
#pragma unroll
    for (int ii = 0; ii < 2; ++ii) {
        int r = w * 32 + ii * 16 + l15;
        ard0[ii] = img_addr(r, kg);
        ard1[ii] = img_addr(r, kg + 16);
    }
#pragma unroll
    for (int f = 0; f < 2; ++f) {
        brd0[f] = img_addr(f * 16 + l15, kg);
        brd1[f] = img_addr(f * 16 + l15, kg + 16);
    }

    f32x4_t acc[2][2];
#pragma unroll
    for (int i = 0; i < 2; ++i)
#pragma unroll
        for (int f = 0; f < 2; ++f)
#pragma unroll
            for (int r = 0; r < 4; ++r) acc[i][f][r] = 0.f;

    const char* asb = (const char*)&As[0];
    const char* bsb = (const char*)&Qs[0];

    float4 qA[4], qB[4];   // slot c&1 holds logical chunk c (static names)

    // prologue: logical chunk 0 staged directly; chunk 1 -> qB, chunk 2 -> qA
    {
        const float* s0 = asrc + ((0 + phase) & 15) * 32;
        float4 v[4];
#pragma unroll
        for (int j = 0; j < 4; ++j) v[j] = *reinterpret_cast<const float4*>(s0 + 4 * j);
        ushort8_t lo, hi;
#pragma unroll
        for (int e = 0; e < 4; ++e) {
            lo[e] = f2bf(v[0][e]); lo[4 + e] = f2bf(v[1][e]);
            hi[e] = f2bf(v[2][e]); hi[4 + e] = f2bf(v[3][e]);
        }
        *(ushort8_t*)((char*)asb + aw0) = lo;
        *(ushort8_t*)((char*)asb + aw1) = hi;
    }
    {
        const float* s1 = asrc + ((1 + phase) & 15) * 32;
#pragma unroll
        for (int j = 0; j < 4; ++j) qB[j] = *reinterpret_cast<const float4*>(s1 + 4 * j);
        const float* s2 = asrc + ((2 + phase) & 15) * 32;
#pragma unroll
        for (int j = 0; j < 4; ++j) qA[j] = *reinterpret_cast<const float4*>(s2 + 4 * j);
    }
    __syncthreads();   // the ONLY barrier: Q visible to all waves

#pragma unroll
    for (int t = 0; t < 16; ++t) {
        const int pt = (t + phase) & 15;   // physical K-chunk / Q-tile index

        Frag fa[2], fb[2];
#pragma unroll
        for (int ii = 0; ii < 2; ++ii) {
            fa[ii].v4[0] = *(const bf16x4_t*)(asb + ard0[ii]);
            fa[ii].v4[1] = *(const bf16x4_t*)(asb + ard1[ii]);
        }
#pragma unroll
        for (int f = 0; f < 2; ++f) {
            fb[f].v4[0] = *(const bf16x4_t*)(bsb + pt * 2048 + brd0[f]);
            fb[f].v4[1] = *(const bf16x4_t*)(bsb + pt * 2048 + brd1[f]);
        }
#pragma unroll
        for (int ii = 0; ii < 2; ++ii)
#pragma unroll
            for (int f = 0; f < 2; ++f)
                acc[ii][f] = __builtin_amdgcn_mfma_f32_16x16x32_bf16(fa[ii].v8, fb[f].v8, acc[ii][f], 0, 0, 0);

        if (t < 15) {
            // convert logical chunk t+1 (slot (t+1)&1), overwrite the single
            // buffer: same-wave in-order DS guarantees this lands after the
            // fa reads above; next iteration's reads see the new data.
            const int slot = (t + 1) & 1;
            ushort8_t lo, hi;
            if (slot == 1) {
#pragma unroll
                for (int e = 0; e < 4; ++e) {
                    lo[e] = f2bf(qB[0][e]); lo[4 + e] = f2bf(qB[1][e]);
                    hi[e] = f2bf(qB[2][e]); hi[4 + e] = f2bf(qB[3][e]);
                }
            } else {
#pragma unroll
                for (int e = 0; e < 4; ++e) {
                    lo[e] = f2bf(qA[0][e]); lo[4 + e] = f2bf(qA[1][e]);
                    hi[e] = f2bf(qA[2][e]); hi[4 + e] = f2bf(qA[3][e]);
                }
            }
            *(ushort8_t*)((char*)asb + aw0) = lo;
            *(ushort8_t*)((char*)asb + aw1) = hi;

            // refill the just-freed slot with logical chunk t+3
            if (t + 3 <= 15) {
                const float* src = asrc + (((t + 3) + phase) & 15) * 32;
                if (slot == 1) {
#pragma unroll
                    for (int j = 0; j < 4; ++j) qB[j] = *reinterpret_cast<const float4*>(src + 4 * j);
                } else {
#pragma unroll
                    for (int j = 0; j < 4; ++j) qA[j] = *reinterpret_cast<const float4*>(src + 4 * j);
                }
            }
        }
    }

    // epilogue: G row = 32 bf16; cols [0,10) = f@Q1, cols [16,26) = f@Q2
    const int rq_ = (lane >> 4) << 2;
#pragma unroll
    for (int ii = 0; ii < 2; ++ii)
#pragma unroll
        for (int r = 0; r < 4; ++r) {
            long grow = row0 + w * 32 + ii * 16 + rq_ + r;
            if (l15 < NCLS && grow < NROWS) {
                G[grow * 32 + l15]      = f2bf(acc[ii][0][r]);
                G[grow * 32 + 16 + l15] = f2bf(acc[ii][1][r]);
            }
        }
}

// ---------------- epilogue: logits = leaky(g1[n1] + g2[n2]), log_softmax ----------------
__global__ __launch_bounds__(256) void k_epi(
    const unsigned short* __restrict__ G,
    const int* __restrict__ n1, const int* __restrict__ n2,
    float* __restrict__ Out) {
    const long i = (long)blockIdx.x * 256 + threadIdx.x;
    if (i >= NROWS) return;
    const ushort8_t* p1 = (const ushort8_t*)(G + (long)n1[i] * 32);
    const ushort8_t* p2 = (const ushort8_t*)(G + (long)n2[i] * 32 + 16);
    ushort8_t a0 = p1[0], a1 = p1[1];
    ushort8_t b0 = p2[0], b1 = p2[1];

    float x[NCLS];
#pragma unroll
    for (int c = 0; c < 8; ++c) x[c] = bf2f(a0[c]) + bf2f(b0[c]);
    x[8] = bf2f(a1[0]) + bf2f(b1[0]);
    x[9] = bf2f(a1[1]) + bf2f(b1[1]);

    float m = -1e30f;
#pragma unroll
    for (int c = 0; c < NCLS; ++c) {
        x[c] = (x[c] >= 0.f) ? x[c] : LEAKY_ALPHA * x[c];
        m = fmaxf(m, x[c]);
    }
    float sum = 0.f;
#pragma unroll
    for (int c = 0; c < NCLS; ++c) sum += __expf(x[c] - m);
    const float lse = m + __logf(sum);
    float2* o = (float2*)(Out + i * NCLS);
#pragma unroll
    for (int j = 0; j < 5; ++j) {
        float2 v = {x[2 * j] - lse, x[2 * j + 1] - lse};
        o[j] = v;
    }
}

extern "C" void kernel_launch(void* const* d_in, const int* in_sizes, int n_in,
                              void* d_out, int out_size, void* d_ws, size_t ws_size,
                              hipStream_t stream) {
    const float* features = (const float*)d_in[0];
    const float* C  = (const float*)d_in[1];
    const float* W  = (const float*)d_in[2];
    const float* V  = (const float*)d_in[3];
    const int*   n1 = (const int*)d_in[4];
    const int*   n2 = (const int*)d_in[5];
    float* out = (float*)d_out;

    char* ws = (char*)d_ws;
    unsigned short* Qimg = (unsigned short*)ws;          // 32 KB
    unsigned short* G = (unsigned short*)(ws + 32768);   // 100000*32*2 = 6.4 MB

    hipLaunchKernelGGL(k_prep, dim3(16), dim3(256), 0, stream, C, W, V, Qimg);
    hipLaunchKernelGGL(k_gemm, dim3((NROWS + 127) / 128), dim3(256), 0, stream,
                       features, Qimg, G);
    hipLaunchKernelGGL(k_epi, dim3((NROWS + 255) / 256), dim3(256), 0, stream,
                       G, n1, n2, out);
}